// Round 17
// baseline (54.019 us; speedup 1.0000x reference)
//
#include <hip/hip_runtime.h>
#include <hip/hip_bf16.h>
#include <stdint.h>

#define BB 16
#define NN 1024
#define MM 1024
#define DD 128
#define VERY_NEG (-1e30f)
#define LOG2E 1.44269504f
#define NCH 8              // 32-m chunks per quarter (256 m)

using bf16x8 = __attribute__((ext_vector_type(8))) short;
using f32x4  = __attribute__((ext_vector_type(4))) float;

__device__ inline unsigned short f2bf(float f) {
    union { float f; uint32_t u; } cv; cv.f = f;
    uint32_t u = cv.u;
    return (unsigned short)((u + 0x7FFFu + ((u >> 16) & 1u)) >> 16);
}
__device__ inline float bf2f(unsigned short s) {
    union { uint32_t u; float f; } cv; cv.u = ((uint32_t)s) << 16;
    return cv.f;
}
#define EXP2F(x) __builtin_amdgcn_exp2f(x)

typedef __attribute__((address_space(3))) unsigned int lds_u32;
typedef const __attribute__((address_space(1))) unsigned int glb_u32;
__device__ __forceinline__ void gl16(const void* g, void* l) {
    __builtin_amdgcn_global_load_lds((glb_u32*)g, (lds_u32*)l, 16, 0, 0);
}

// ---- fused prep: blocks [0,4096) = q row-prep; [4096,4352) = mem tiles
//      (single mem read: dot+c1s+mb+mt from one 64x128 tile load) ----
__global__ __launch_bounds__(256) void prep_all(
    const float* __restrict__ q, const float* __restrict__ mem,
    const float* __restrict__ wq, const float* __restrict__ wm,
    const float* __restrict__ wqm, const int* __restrict__ mmask,
    float* __restrict__ a, float* __restrict__ c1s,
    unsigned short* __restrict__ qp, unsigned short* __restrict__ mb,
    unsigned short* __restrict__ mt)
{
    __shared__ unsigned short tile[64][132];
    int tid = threadIdx.x;
    if (blockIdx.x < 4096) {
        // q rows: wave = one row, lane = 2 elems
        int row = blockIdx.x * 4 + (tid >> 6);
        int lane = tid & 63;
        const float* src = q + (size_t)row * DD;
        float2 v  = *(const float2*)(src + lane * 2);
        float2 w2 = *(const float2*)(wq + lane * 2);
        float dot = v.x * w2.x + v.y * w2.y;
        #pragma unroll
        for (int o = 32; o; o >>= 1) dot += __shfl_xor(dot, o);
        if (lane == 0) a[row] = dot;
        float2 wv = *(const float2*)(wqm + lane * 2);
        ushort2 o2;
        o2.x = f2bf(v.x * wv.x * LOG2E);
        o2.y = f2bf(v.y * wv.y * LOG2E);
        *(ushort2*)(qp + (size_t)row * DD + lane * 2) = o2;
    } else {
        // mem tile: 64 rows x 128 d, read once
        int bid = blockIdx.x - 4096;
        int b = bid >> 4, mtile = bid & 15;
        int m0 = mtile * 64;
        int lane32 = tid & 31;
        float4 wmv = *(const float4*)(wm + lane32 * 4);
        #pragma unroll
        for (int rr = 0; rr < 8; rr++) {
            int r = rr * 8 + (tid >> 5);
            int row = b * MM + m0 + r;
            float4 v = *(const float4*)(mem + (size_t)row * DD + lane32 * 4);
            float dot = v.x * wmv.x + v.y * wmv.y + v.z * wmv.z + v.w * wmv.w;
            #pragma unroll
            for (int o = 16; o; o >>= 1) dot += __shfl_xor(dot, o);
            if (lane32 == 0) {
                int mmv = mmask[row];
                c1s[row] = (dot + (mmv ? 0.f : VERY_NEG)) * LOG2E;
            }
            ushort4 o4;
            o4.x = f2bf(v.x); o4.y = f2bf(v.y); o4.z = f2bf(v.z); o4.w = f2bf(v.w);
            *(ushort4*)(mb + (size_t)row * DD + lane32 * 4) = o4;
            *(ushort4*)(&tile[r][lane32 * 4]) = o4;
        }
        __syncthreads();
        // emit mt[b][d][m0..m0+63] from LDS
        int d = tid >> 1, mh = (tid & 1) * 32;
        unsigned short* dst = mt + ((size_t)b * DD + d) * MM + m0 + mh;
        #pragma unroll
        for (int mm = 0; mm < 32; mm += 4) {
            ushort4 o4;
            o4.x = tile[mh + mm + 0][d];
            o4.y = tile[mh + mm + 1][d];
            o4.z = tile[mh + mm + 2][d];
            o4.w = tile[mh + mm + 3][d];
            *(ushort4*)(dst + mm) = o4;
        }
    }
}

// ---- flash main (R14-exact): grid 512, 4 waves/block, 32 q/wave, 256-m quarter.
//      2-buffer staging + counted vmcnt(4) depth-1 prefetch + raw barriers.
//      DEFER-MAX (THR=8). bf16 partials + (tmax, l'). ----
__global__ __launch_bounds__(256, 3) void flash_fwd(
    const unsigned short* __restrict__ qp, const unsigned short* __restrict__ mb,
    const unsigned short* __restrict__ mt,
    const float* __restrict__ c1s, const int* __restrict__ qmask,
    unsigned short* __restrict__ Opart, float2* __restrict__ ml)
{
    __shared__ unsigned short stg[2][16 * 512];        // 32 KB: 2 bufs x 16 1KB slots
    __shared__ unsigned short pl[4][2][16][40];        // 10 KB
    __shared__ float c1L[256];                         // 1 KB

    int tid = threadIdx.x;
    int w = tid >> 6, lane = tid & 63;
    int g = lane >> 4, qi = lane & 15;
    int wk = (blockIdx.x & 7) * 64 + (blockIdx.x >> 3);
    int b = wk >> 5, mh = (wk >> 3) & 3, nt = wk & 7;
    int n0q = nt * 128 + w * 32;
    int mbase = mh * 256;

    const unsigned short* mbB = mb + (size_t)b * MM * DD;
    const unsigned short* mtB = mt + (size_t)b * DD * MM;

    if (tid < 64) {
        float4 cv = *(const float4*)(c1s + b * MM + mbase + tid * 4);
        *(float4*)&c1L[tid * 4] = cv;
    }

    const unsigned short* qpb = qp + ((size_t)b * NN + n0q) * DD;
    bf16x8 qf[2][4];
    #pragma unroll
    for (int qt = 0; qt < 2; qt++)
        #pragma unroll
        for (int kc = 0; kc < 4; kc++)
            qf[qt][kc] = *(const bf16x8*)(qpb + (qt * 16 + qi) * DD + kc * 32 + g * 8);

    int qm[2];
    qm[0] = qmask[b * NN + n0q + qi];
    qm[1] = qmask[b * NN + n0q + 16 + qi];

    float m_run[2] = {-INFINITY, -INFINITY}, l_run[2] = {0.f, 0.f};
    float tmax[2]  = {-INFINITY, -INFINITY};
    f32x4 o[2][8];
    #pragma unroll
    for (int qt = 0; qt < 2; qt++)
        #pragma unroll
        for (int d2 = 0; d2 < 8; d2++) o[qt][d2] = (f32x4){0.f, 0.f, 0.f, 0.f};

    auto stage = [&](int m0, unsigned short* buf) {
        #pragma unroll
        for (int i = 0; i < 4; i++) {
            int j = w * 4 + i;
            if (j < 8) {
                const unsigned short* gsrc = mbB
                    + (size_t)(m0 + (j >> 2) * 16 + (lane & 15)) * DD
                    + (j & 3) * 32 + (lane >> 4) * 8;
                gl16(gsrc, buf + j * 512);
            } else {
                const unsigned short* gsrc = mtB
                    + (size_t)((j - 8) * 16 + (lane & 15)) * MM + m0 + (lane >> 4) * 8;
                gl16(gsrc, buf + j * 512);
            }
        }
    };

    unsigned short* bufA = stg[0];   // current chunk
    unsigned short* bufB = stg[1];   // prefetch target

    stage(mbase, bufA);
    __syncthreads();   // one-time full drain: chunk 0 + c1L resident

    #pragma unroll
    for (int ch = 0; ch < NCH; ch++) {
        int m0 = mbase + ch * 32;
        if (ch + 1 < NCH) {
            stage(m0 + 32, bufB);   // 4 gl16 stay in flight across this chunk's compute
            asm volatile("s_waitcnt vmcnt(4)" ::: "memory");   // own bufA slots done
        } else {
            asm volatile("s_waitcnt vmcnt(0)" ::: "memory");
        }
        __builtin_amdgcn_sched_barrier(0);
        __builtin_amdgcn_s_barrier();      // all waves' bufA slots complete
        __builtin_amdgcn_sched_barrier(0);

        const unsigned short* bc = bufA;

        // QK: S^T tiles (16m x 16q), 2 t-tiles x 2 qt; 1 K-read feeds 2 MFMAs
        f32x4 st[2][2];
        #pragma unroll
        for (int qt = 0; qt < 2; qt++) { st[qt][0] = (f32x4){0,0,0,0}; st[qt][1] = (f32x4){0,0,0,0}; }
        #pragma unroll
        for (int t = 0; t < 2; t++) {
            #pragma unroll
            for (int kc = 0; kc < 4; kc++) {
                bf16x8 af = *(const bf16x8*)(bc + ((t * 4 + kc) * 64 + lane) * 8);
                #pragma unroll
                for (int qt = 0; qt < 2; qt++)
                    st[qt][t] = __builtin_amdgcn_mfma_f32_16x16x32_bf16(af, qf[qt][kc], st[qt][t], 0, 0, 0);
            }
        }
        // online softmax per q-subtile, defer-max
        #pragma unroll
        for (int qt = 0; qt < 2; qt++) {
            float sv[2][4];
            float cmax = -INFINITY;
            #pragma unroll
            for (int t = 0; t < 2; t++) {
                float4 c1v = *(const float4*)&c1L[ch * 32 + t * 16 + g * 4];
                float cc4[4] = {c1v.x, c1v.y, c1v.z, c1v.w};
                #pragma unroll
                for (int i = 0; i < 4; i++) {
                    float s = qm[qt] ? (st[qt][t][i] + cc4[i]) : 0.f;
                    sv[t][i] = s;
                    cmax = fmaxf(cmax, s);
                }
            }
            cmax = fmaxf(cmax, __shfl_xor(cmax, 16));
            cmax = fmaxf(cmax, __shfl_xor(cmax, 32));
            tmax[qt] = fmaxf(tmax[qt], cmax);

            if (__any(cmax > m_run[qt] + 8.f)) {
                float m_new = fmaxf(m_run[qt], cmax);
                float alpha = EXP2F(m_run[qt] - m_new);
                m_run[qt] = m_new;
                l_run[qt] *= alpha;
                float aL[4];
                #pragma unroll
                for (int i = 0; i < 4; i++) aL[i] = __shfl(alpha, g * 4 + i);
                #pragma unroll
                for (int d2 = 0; d2 < 8; d2++) {
                    #pragma unroll
                    for (int i = 0; i < 4; i++) o[qt][d2][i] *= aL[i];
                }
            }

            float psum = 0.f;
            #pragma unroll
            for (int t = 0; t < 2; t++) {
                unsigned short pe[4];
                #pragma unroll
                for (int i = 0; i < 4; i++) {
                    float p = EXP2F(sv[t][i] - m_run[qt]);
                    psum += p;
                    pe[i] = f2bf(p);
                }
                ushort4 pw2; pw2.x = pe[0]; pw2.y = pe[1]; pw2.z = pe[2]; pw2.w = pe[3];
                *(ushort4*)(&pl[w][qt][qi][t * 16 + g * 4]) = pw2;
            }
            psum += __shfl_xor(psum, 16);
            psum += __shfl_xor(psum, 32);
            l_run[qt] += psum;
        }

        __builtin_amdgcn_sched_barrier(0);
        // PV: one A-frag per qt (K=32); 1 V-read feeds 2 MFMAs; pure accumulate
        bf16x8 pa[2];
        pa[0] = *(const bf16x8*)(&pl[w][0][qi][g * 8]);
        pa[1] = *(const bf16x8*)(&pl[w][1][qi][g * 8]);
        #pragma unroll
        for (int d2 = 0; d2 < 8; d2++) {
            bf16x8 vf = *(const bf16x8*)(bc + ((8 + d2) * 64 + lane) * 8);
            #pragma unroll
            for (int qt = 0; qt < 2; qt++)
                o[qt][d2] = __builtin_amdgcn_mfma_f32_16x16x32_bf16(pa[qt], vf, o[qt][d2], 0, 0, 0);
        }

        // end-of-chunk barrier: all waves done with bufA before partner re-stages it
        __builtin_amdgcn_sched_barrier(0);
        __builtin_amdgcn_s_barrier();
        __builtin_amdgcn_sched_barrier(0);

        unsigned short* tmp = bufA; bufA = bufB; bufB = tmp;
    }

    // ---- epilogue: l-normalized bf16 partials + (tmax, l * 2^(m_run - tmax)) ----
    #pragma unroll
    for (int qt = 0; qt < 2; qt++) {
        float inv[4];
        #pragma unroll
        for (int i = 0; i < 4; i++) inv[i] = 1.f / __shfl(l_run[qt], g * 4 + i);
        size_t rbase = ((size_t)mh * BB + b) * NN + n0q + qt * 16;
        #pragma unroll
        for (int d2 = 0; d2 < 8; d2++) {
            #pragma unroll
            for (int i = 0; i < 4; i++)
                Opart[(rbase + g * 4 + i) * DD + d2 * 16 + qi] = f2bf(o[qt][d2][i] * inv[i]);
        }
        if (g == 0) {
            float2 v;
            v.x = tmax[qt];
            v.y = l_run[qt] * EXP2F(m_run[qt] - tmax[qt]);
            ml[rbase + qi] = v;
        }
    }
}

// ---- rowmax from ml quarters (same absorbed -1e30 math as merge) ----
__device__ __forceinline__ float row_max_of(const float2* __restrict__ ml,
                                            const float* __restrict__ a,
                                            const int* __restrict__ qmask, int R)
{
    float M = fmaxf(fmaxf(ml[0 * BB * NN + R].x, ml[1 * BB * NN + R].x),
                    fmaxf(ml[2 * BB * NN + R].x, ml[3 * BB * NN + R].x));
    return M * (1.f / LOG2E) + a[R] + (qmask[R] ? 0.f : VERY_NEG);
}

// ---- m2q partials (self-contained: rowmax derived from ml) ----
__global__ __launch_bounds__(256) void m2q_partial(
    const float2* __restrict__ ml, const float* __restrict__ a,
    const int* __restrict__ qmask, const float* __restrict__ query,
    float* __restrict__ partial, float* __restrict__ Zbuf)
{
    int bid = blockIdx.x;
    int b = bid >> 4, ch = bid & 15;
    int tid = threadIdx.x, lane = tid & 63, wv = tid >> 6;
    __shared__ float red[8];
    __shared__ float pe[64];
    __shared__ float acc1[128];

    float rm[4];
    #pragma unroll
    for (int i = 0; i < 4; i++)
        rm[i] = row_max_of(ml, a, qmask, b * NN + tid * 4 + i);
    float mx = fmaxf(fmaxf(rm[0], rm[1]), fmaxf(rm[2], rm[3]));
    #pragma unroll
    for (int o = 32; o; o >>= 1) mx = fmaxf(mx, __shfl_xor(mx, o));
    if (lane == 0) red[wv] = mx;
    __syncthreads();
    mx = fmaxf(fmaxf(red[0], red[1]), fmaxf(red[2], red[3]));
    float ls = __expf(rm[0] - mx) + __expf(rm[1] - mx) + __expf(rm[2] - mx) + __expf(rm[3] - mx);
    #pragma unroll
    for (int o = 32; o; o >>= 1) ls += __shfl_xor(ls, o);
    if (lane == 0) red[4 + wv] = ls;
    if (tid < 64)
        pe[tid] = __expf(row_max_of(ml, a, qmask, b * NN + ch * 64 + tid) - mx);
    __syncthreads();
    float Z = (red[4] + red[5]) + (red[6] + red[7]);

    int d = tid & 127, h = tid >> 7;
    const float* qb = query + ((size_t)b * NN + ch * 64 + h * 32) * DD + d;
    float acc = 0.f;
    #pragma unroll 8
    for (int n = 0; n < 32; n++) acc += pe[h * 32 + n] * qb[(size_t)n * DD];
    if (h) acc1[d] = acc;
    __syncthreads();
    if (!h) partial[(b * 16 + ch) * DD + d] = acc + acc1[d];
    if (tid == 0) Zbuf[b] = Z;
}

// ---- fused tail: bid<8192 -> merge (out1); else -> bcast (out2) ----
__global__ __launch_bounds__(256) void tail_kernel(
    const unsigned short* __restrict__ Opart, const float2* __restrict__ ml,
    const float* __restrict__ partial, const float* __restrict__ Zbuf,
    float* __restrict__ out1, float4* __restrict__ out2)
{
    int bid = blockIdx.x;
    if (bid < 8192) {
        int R = bid * 2 + (threadIdx.x >> 7);
        int d = threadIdx.x & 127;
        float2 mlv[4];
        float M = -INFINITY;
        #pragma unroll
        for (int k = 0; k < 4; k++) {
            mlv[k] = ml[(size_t)k * BB * NN + R];
            M = fmaxf(M, mlv[k].x);
        }
        float wgt[4], Z = 0.f;
        #pragma unroll
        for (int k = 0; k < 4; k++) {
            wgt[k] = mlv[k].y * EXP2F(mlv[k].x - M);
            Z += wgt[k];
        }
        float acc = 0.f;
        #pragma unroll
        for (int k = 0; k < 4; k++)
            acc += bf2f(Opart[((size_t)k * BB * NN + R) * DD + d]) * wgt[k];
        out1[(size_t)R * DD + d] = acc / Z;
    } else {
        __shared__ float m2qL[128];
        int i = (bid - 8192) * 256 + threadIdx.x;
        int b = i >> 15;
        int tid = threadIdx.x;
        if (tid < 128) {
            float s = 0.f;
            #pragma unroll
            for (int ch = 0; ch < 16; ch++) s += partial[(b * 16 + ch) * DD + tid];
            m2qL[tid] = s / Zbuf[b];
        }
        __syncthreads();
        out2[i] = ((const float4*)m2qL)[i & 31];
    }
}

extern "C" void kernel_launch(void* const* d_in, const int* in_sizes, int n_in,
                              void* d_out, int out_size, void* d_ws, size_t ws_size,
                              hipStream_t stream)
{
    const float* query  = (const float*)d_in[0];
    const float* memory = (const float*)d_in[1];
    const float* w_q    = (const float*)d_in[2];
    const float* w_m    = (const float*)d_in[3];
    const float* w_qm   = (const float*)d_in[4];
    const int*   qmask  = (const int*)d_in[5];
    const int*   mmask  = (const int*)d_in[6];
    float* out1 = (float*)d_out;
    float* out2 = out1 + (size_t)BB * NN * DD;

    char* ws = (char*)d_ws;
    float* a       = (float*)ws;                 // B*N
    float* c1s     = a + BB * NN;                // B*M
    float* partial = c1s + BB * MM;              // B*16*D
    float* Zbuf    = partial + BB * 16 * DD;     // B
    unsigned short* qp = (unsigned short*)(ws + (1 << 20));
    unsigned short* mb = qp + (size_t)BB * NN * DD;
    unsigned short* mt = mb + (size_t)BB * MM * DD;
    unsigned short* Opart = (unsigned short*)(ws + (16u << 20));   // 4 * B*N*D bf16
    float2* mlbuf  = (float2*)(ws + (32u << 20));                  // 4 * B*N float2

    prep_all<<<dim3(4096 + 256), 256, 0, stream>>>(query, memory, w_q, w_m, w_qm, mmask,
                                                   a, c1s, qp, mb, mt);
    flash_fwd<<<dim3(512), 256, 0, stream>>>(qp, mb, mt, c1s, qmask, Opart, mlbuf);
    m2q_partial<<<dim3(BB * 16), 256, 0, stream>>>(mlbuf, a, qmask, query, partial, Zbuf);
    tail_kernel<<<dim3(8192 + 2048), 256, 0, stream>>>(Opart, mlbuf, partial, Zbuf,
                                                       out1, (float4*)out2);
}

// Round 18
// 51.863 us; speedup vs baseline: 1.0416x; 1.0416x over previous
//
#include <hip/hip_runtime.h>
#include <hip/hip_bf16.h>
#include <stdint.h>

#define BB 16
#define NN 1024
#define MM 1024
#define DD 128
#define VERY_NEG (-1e30f)
#define LOG2E 1.44269504f
#define NCH 8              // 32-m chunks per quarter (256 m)

using bf16x8 = __attribute__((ext_vector_type(8))) short;
using f32x4  = __attribute__((ext_vector_type(4))) float;

__device__ inline unsigned short f2bf(float f) {
    union { float f; uint32_t u; } cv; cv.f = f;
    uint32_t u = cv.u;
    return (unsigned short)((u + 0x7FFFu + ((u >> 16) & 1u)) >> 16);
}
__device__ inline float bf2f(unsigned short s) {
    union { uint32_t u; float f; } cv; cv.u = ((uint32_t)s) << 16;
    return cv.f;
}
#define EXP2F(x) __builtin_amdgcn_exp2f(x)

typedef __attribute__((address_space(3))) unsigned int lds_u32;
typedef const __attribute__((address_space(1))) unsigned int glb_u32;
__device__ __forceinline__ void gl16(const void* g, void* l) {
    __builtin_amdgcn_global_load_lds((glb_u32*)g, (lds_u32*)l, 16, 0, 0);
}

// ---- fused prep: blocks [0,8192) = row-prep; [8192,8704) = transpose ----
__global__ __launch_bounds__(256) void prep_all(
    const float* __restrict__ q, const float* __restrict__ mem,
    const float* __restrict__ wq, const float* __restrict__ wm,
    const float* __restrict__ wqm, const int* __restrict__ mmask,
    float* __restrict__ a, float* __restrict__ c1s,
    unsigned short* __restrict__ qp, unsigned short* __restrict__ mb,
    unsigned short* __restrict__ mt)
{
    __shared__ unsigned short t[64][72];
    if (blockIdx.x < 8192) {
        int wave = (blockIdx.x * 256 + threadIdx.x) >> 6;
        int lane = threadIdx.x & 63;
        bool is_q = wave < BB * NN;
        int row = is_q ? wave : wave - BB * NN;
        const float* src = (is_q ? q : mem) + (size_t)row * DD;
        const float* wd  = is_q ? wq : wm;
        float2 v  = *(const float2*)(src + lane * 2);
        float2 w2 = *(const float2*)(wd + lane * 2);
        float dot = v.x * w2.x + v.y * w2.y;
        #pragma unroll
        for (int o = 32; o; o >>= 1) dot += __shfl_xor(dot, o);
        if (lane == 0) {
            if (is_q) a[row] = dot;
            else {
                int mm = mmask[row];
                c1s[row] = (dot + (mm ? 0.f : VERY_NEG)) * LOG2E;
            }
        }
        float2 s2 = v;
        if (is_q) {
            float2 wv = *(const float2*)(wqm + lane * 2);
            s2.x *= wv.x * LOG2E; s2.y *= wv.y * LOG2E;
        }
        ushort2 o2; o2.x = f2bf(s2.x); o2.y = f2bf(s2.y);
        *(ushort2*)((is_q ? qp : mb) + (size_t)row * DD + lane * 2) = o2;
    } else {
        int bid = blockIdx.x - 8192;
        int dt = bid & 1, mtile = (bid >> 1) & 15, b = bid >> 5;
        int d0 = dt * 64, m0 = mtile * 64;
        int tid = threadIdx.x;
        int cc = tid & 63, rr = tid >> 6;
        #pragma unroll
        for (int r = 0; r < 64; r += 4) {
            float v = mem[((size_t)b * MM + m0 + r + rr) * DD + d0 + cc];
            t[cc][r + rr] = f2bf(v);
        }
        __syncthreads();
        #pragma unroll
        for (int r = 0; r < 64; r += 4) {
            mt[((size_t)b * DD + d0 + r + rr) * MM + m0 + cc] = t[r + rr][cc];
        }
    }
}

// ---- flash main: grid 512, 4 waves/block, 32 q/wave, 256-m quarter.
//      TWO-buffer staging (43KB LDS -> 3 blocks/CU) + counted vmcnt(4)
//      depth-1 prefetch + raw barriers (no mid-loop vmcnt(0) drain).
//      DEFER-MAX (THR=8). bf16 partials + (tmax, l'). ----
__global__ __launch_bounds__(256, 3) void flash_fwd(
    const unsigned short* __restrict__ qp, const unsigned short* __restrict__ mb,
    const unsigned short* __restrict__ mt,
    const float* __restrict__ c1s, const int* __restrict__ qmask,
    unsigned short* __restrict__ Opart, float2* __restrict__ ml)
{
    __shared__ unsigned short stg[2][16 * 512];        // 32 KB: 2 bufs x 16 1KB slots
    __shared__ unsigned short pl[4][2][16][40];        // 10 KB
    __shared__ float c1L[256];                         // 1 KB

    int tid = threadIdx.x;
    int w = tid >> 6, lane = tid & 63;
    int g = lane >> 4, qi = lane & 15;
    int wk = (blockIdx.x & 7) * 64 + (blockIdx.x >> 3);
    int b = wk >> 5, mh = (wk >> 3) & 3, nt = wk & 7;
    int n0q = nt * 128 + w * 32;
    int mbase = mh * 256;

    const unsigned short* mbB = mb + (size_t)b * MM * DD;
    const unsigned short* mtB = mt + (size_t)b * DD * MM;

    if (tid < 64) {
        float4 cv = *(const float4*)(c1s + b * MM + mbase + tid * 4);
        *(float4*)&c1L[tid * 4] = cv;
    }

    const unsigned short* qpb = qp + ((size_t)b * NN + n0q) * DD;
    bf16x8 qf[2][4];
    #pragma unroll
    for (int qt = 0; qt < 2; qt++)
        #pragma unroll
        for (int kc = 0; kc < 4; kc++)
            qf[qt][kc] = *(const bf16x8*)(qpb + (qt * 16 + qi) * DD + kc * 32 + g * 8);

    int qm[2];
    qm[0] = qmask[b * NN + n0q + qi];
    qm[1] = qmask[b * NN + n0q + 16 + qi];

    float m_run[2] = {-INFINITY, -INFINITY}, l_run[2] = {0.f, 0.f};
    float tmax[2]  = {-INFINITY, -INFINITY};
    f32x4 o[2][8];
    #pragma unroll
    for (int qt = 0; qt < 2; qt++)
        #pragma unroll
        for (int d2 = 0; d2 < 8; d2++) o[qt][d2] = (f32x4){0.f, 0.f, 0.f, 0.f};

    auto stage = [&](int m0, unsigned short* buf) {
        #pragma unroll
        for (int i = 0; i < 4; i++) {
            int j = w * 4 + i;
            if (j < 8) {
                const unsigned short* gsrc = mbB
                    + (size_t)(m0 + (j >> 2) * 16 + (lane & 15)) * DD
                    + (j & 3) * 32 + (lane >> 4) * 8;
                gl16(gsrc, buf + j * 512);
            } else {
                const unsigned short* gsrc = mtB
                    + (size_t)((j - 8) * 16 + (lane & 15)) * MM + m0 + (lane >> 4) * 8;
                gl16(gsrc, buf + j * 512);
            }
        }
    };

    unsigned short* bufA = stg[0];   // current chunk
    unsigned short* bufB = stg[1];   // prefetch target

    stage(mbase, bufA);
    __syncthreads();   // one-time full drain: chunk 0 + c1L resident

    #pragma unroll
    for (int ch = 0; ch < NCH; ch++) {
        int m0 = mbase + ch * 32;
        if (ch + 1 < NCH) {
            stage(m0 + 32, bufB);   // 4 gl16 stay in flight across this chunk's compute
            asm volatile("s_waitcnt vmcnt(4)" ::: "memory");   // own bufA slots done
        } else {
            asm volatile("s_waitcnt vmcnt(0)" ::: "memory");
        }
        __builtin_amdgcn_sched_barrier(0);
        __builtin_amdgcn_s_barrier();      // all waves' bufA slots complete
        __builtin_amdgcn_sched_barrier(0);

        const unsigned short* bc = bufA;

        // QK: S^T tiles (16m x 16q), 2 t-tiles x 2 qt; 1 K-read feeds 2 MFMAs
        f32x4 st[2][2];
        #pragma unroll
        for (int qt = 0; qt < 2; qt++) { st[qt][0] = (f32x4){0,0,0,0}; st[qt][1] = (f32x4){0,0,0,0}; }
        #pragma unroll
        for (int t = 0; t < 2; t++) {
            #pragma unroll
            for (int kc = 0; kc < 4; kc++) {
                bf16x8 af = *(const bf16x8*)(bc + ((t * 4 + kc) * 64 + lane) * 8);
                #pragma unroll
                for (int qt = 0; qt < 2; qt++)
                    st[qt][t] = __builtin_amdgcn_mfma_f32_16x16x32_bf16(af, qf[qt][kc], st[qt][t], 0, 0, 0);
            }
        }
        // online softmax per q-subtile, defer-max
        #pragma unroll
        for (int qt = 0; qt < 2; qt++) {
            float sv[2][4];
            float cmax = -INFINITY;
            #pragma unroll
            for (int t = 0; t < 2; t++) {
                float4 c1v = *(const float4*)&c1L[ch * 32 + t * 16 + g * 4];
                float cc4[4] = {c1v.x, c1v.y, c1v.z, c1v.w};
                #pragma unroll
                for (int i = 0; i < 4; i++) {
                    float s = qm[qt] ? (st[qt][t][i] + cc4[i]) : 0.f;
                    sv[t][i] = s;
                    cmax = fmaxf(cmax, s);
                }
            }
            cmax = fmaxf(cmax, __shfl_xor(cmax, 16));
            cmax = fmaxf(cmax, __shfl_xor(cmax, 32));
            tmax[qt] = fmaxf(tmax[qt], cmax);

            if (__any(cmax > m_run[qt] + 8.f)) {
                float m_new = fmaxf(m_run[qt], cmax);
                float alpha = EXP2F(m_run[qt] - m_new);
                m_run[qt] = m_new;
                l_run[qt] *= alpha;
                float aL[4];
                #pragma unroll
                for (int i = 0; i < 4; i++) aL[i] = __shfl(alpha, g * 4 + i);
                #pragma unroll
                for (int d2 = 0; d2 < 8; d2++) {
                    #pragma unroll
                    for (int i = 0; i < 4; i++) o[qt][d2][i] *= aL[i];
                }
            }

            float psum = 0.f;
            #pragma unroll
            for (int t = 0; t < 2; t++) {
                unsigned short pe[4];
                #pragma unroll
                for (int i = 0; i < 4; i++) {
                    float p = EXP2F(sv[t][i] - m_run[qt]);
                    psum += p;
                    pe[i] = f2bf(p);
                }
                ushort4 pw2; pw2.x = pe[0]; pw2.y = pe[1]; pw2.z = pe[2]; pw2.w = pe[3];
                *(ushort4*)(&pl[w][qt][qi][t * 16 + g * 4]) = pw2;
            }
            psum += __shfl_xor(psum, 16);
            psum += __shfl_xor(psum, 32);
            l_run[qt] += psum;
        }

        __builtin_amdgcn_sched_barrier(0);
        // PV: one A-frag per qt (K=32); 1 V-read feeds 2 MFMAs; pure accumulate
        bf16x8 pa[2];
        pa[0] = *(const bf16x8*)(&pl[w][0][qi][g * 8]);
        pa[1] = *(const bf16x8*)(&pl[w][1][qi][g * 8]);
        #pragma unroll
        for (int d2 = 0; d2 < 8; d2++) {
            bf16x8 vf = *(const bf16x8*)(bc + ((8 + d2) * 64 + lane) * 8);
            #pragma unroll
            for (int qt = 0; qt < 2; qt++)
                o[qt][d2] = __builtin_amdgcn_mfma_f32_16x16x32_bf16(pa[qt], vf, o[qt][d2], 0, 0, 0);
        }

        // end-of-chunk barrier: all waves done with bufA before partner re-stages it
        __builtin_amdgcn_sched_barrier(0);
        __builtin_amdgcn_s_barrier();
        __builtin_amdgcn_sched_barrier(0);

        unsigned short* tmp = bufA; bufA = bufB; bufB = tmp;
    }

    // ---- epilogue: l-normalized bf16 partials + (tmax, l * 2^(m_run - tmax)) ----
    #pragma unroll
    for (int qt = 0; qt < 2; qt++) {
        float inv[4];
        #pragma unroll
        for (int i = 0; i < 4; i++) inv[i] = 1.f / __shfl(l_run[qt], g * 4 + i);
        size_t rbase = ((size_t)mh * BB + b) * NN + n0q + qt * 16;
        #pragma unroll
        for (int d2 = 0; d2 < 8; d2++) {
            #pragma unroll
            for (int i = 0; i < 4; i++)
                Opart[(rbase + g * 4 + i) * DD + d2 * 16 + qi] = f2bf(o[qt][d2][i] * inv[i]);
        }
        if (g == 0) {
            float2 v;
            v.x = tmax[qt];
            v.y = l_run[qt] * EXP2F(m_run[qt] - tmax[qt]);
            ml[rbase + qi] = v;
        }
    }
}

// ---- rowmax from ml quarters (same absorbed -1e30 math as merge) ----
__device__ __forceinline__ float row_max_of(const float2* __restrict__ ml,
                                            const float* __restrict__ a,
                                            const int* __restrict__ qmask, int R)
{
    float M = fmaxf(fmaxf(ml[0 * BB * NN + R].x, ml[1 * BB * NN + R].x),
                    fmaxf(ml[2 * BB * NN + R].x, ml[3 * BB * NN + R].x));
    return M * (1.f / LOG2E) + a[R] + (qmask[R] ? 0.f : VERY_NEG);
}

// ---- m2q partials (self-contained: rowmax derived from ml) ----
__global__ __launch_bounds__(256) void m2q_partial(
    const float2* __restrict__ ml, const float* __restrict__ a,
    const int* __restrict__ qmask, const float* __restrict__ query,
    float* __restrict__ partial, float* __restrict__ Zbuf)
{
    int bid = blockIdx.x;
    int b = bid >> 4, ch = bid & 15;
    int tid = threadIdx.x, lane = tid & 63, wv = tid >> 6;
    __shared__ float red[8];
    __shared__ float pe[64];
    __shared__ float acc1[128];

    float rm[4];
    #pragma unroll
    for (int i = 0; i < 4; i++)
        rm[i] = row_max_of(ml, a, qmask, b * NN + tid * 4 + i);
    float mx = fmaxf(fmaxf(rm[0], rm[1]), fmaxf(rm[2], rm[3]));
    #pragma unroll
    for (int o = 32; o; o >>= 1) mx = fmaxf(mx, __shfl_xor(mx, o));
    if (lane == 0) red[wv] = mx;
    __syncthreads();
    mx = fmaxf(fmaxf(red[0], red[1]), fmaxf(red[2], red[3]));
    float ls = __expf(rm[0] - mx) + __expf(rm[1] - mx) + __expf(rm[2] - mx) + __expf(rm[3] - mx);
    #pragma unroll
    for (int o = 32; o; o >>= 1) ls += __shfl_xor(ls, o);
    if (lane == 0) red[4 + wv] = ls;
    if (tid < 64)
        pe[tid] = __expf(row_max_of(ml, a, qmask, b * NN + ch * 64 + tid) - mx);
    __syncthreads();
    float Z = (red[4] + red[5]) + (red[6] + red[7]);

    int d = tid & 127, h = tid >> 7;
    const float* qb = query + ((size_t)b * NN + ch * 64 + h * 32) * DD + d;
    float acc = 0.f;
    #pragma unroll 8
    for (int n = 0; n < 32; n++) acc += pe[h * 32 + n] * qb[(size_t)n * DD];
    if (h) acc1[d] = acc;
    __syncthreads();
    if (!h) partial[(b * 16 + ch) * DD + d] = acc + acc1[d];
    if (tid == 0) Zbuf[b] = Z;
}

// ---- fused tail: bid<8192 -> merge (out1); else -> bcast (out2) ----
__global__ __launch_bounds__(256) void tail_kernel(
    const unsigned short* __restrict__ Opart, const float2* __restrict__ ml,
    const float* __restrict__ partial, const float* __restrict__ Zbuf,
    float* __restrict__ out1, float4* __restrict__ out2)
{
    int bid = blockIdx.x;
    if (bid < 8192) {
        int R = bid * 2 + (threadIdx.x >> 7);
        int d = threadIdx.x & 127;
        float2 mlv[4];
        float M = -INFINITY;
        #pragma unroll
        for (int k = 0; k < 4; k++) {
            mlv[k] = ml[(size_t)k * BB * NN + R];
            M = fmaxf(M, mlv[k].x);
        }
        float wgt[4], Z = 0.f;
        #pragma unroll
        for (int k = 0; k < 4; k++) {
            wgt[k] = mlv[k].y * EXP2F(mlv[k].x - M);
            Z += wgt[k];
        }
        float acc = 0.f;
        #pragma unroll
        for (int k = 0; k < 4; k++)
            acc += bf2f(Opart[((size_t)k * BB * NN + R) * DD + d]) * wgt[k];
        out1[(size_t)R * DD + d] = acc / Z;
    } else {
        __shared__ float m2qL[128];
        int i = (bid - 8192) * 256 + threadIdx.x;
        int b = i >> 15;
        int tid = threadIdx.x;
        if (tid < 128) {
            float s = 0.f;
            #pragma unroll
            for (int ch = 0; ch < 16; ch++) s += partial[(b * 16 + ch) * DD + tid];
            m2qL[tid] = s / Zbuf[b];
        }
        __syncthreads();
        out2[i] = ((const float4*)m2qL)[i & 31];
    }
}

extern "C" void kernel_launch(void* const* d_in, const int* in_sizes, int n_in,
                              void* d_out, int out_size, void* d_ws, size_t ws_size,
                              hipStream_t stream)
{
    const float* query  = (const float*)d_in[0];
    const float* memory = (const float*)d_in[1];
    const float* w_q    = (const float*)d_in[2];
    const float* w_m    = (const float*)d_in[3];
    const float* w_qm   = (const float*)d_in[4];
    const int*   qmask  = (const int*)d_in[5];
    const int*   mmask  = (const int*)d_in[6];
    float* out1 = (float*)d_out;
    float* out2 = out1 + (size_t)BB * NN * DD;

    char* ws = (char*)d_ws;
    float* a       = (float*)ws;                 // B*N
    float* c1s     = a + BB * NN;                // B*M
    float* partial = c1s + BB * MM;              // B*16*D
    float* Zbuf    = partial + BB * 16 * DD;     // B
    unsigned short* qp = (unsigned short*)(ws + (1 << 20));
    unsigned short* mb = qp + (size_t)BB * NN * DD;
    unsigned short* mt = mb + (size_t)BB * MM * DD;
    unsigned short* Opart = (unsigned short*)(ws + (16u << 20));   // 4 * B*N*D bf16
    float2* mlbuf  = (float2*)(ws + (32u << 20));                  // 4 * B*N float2

    prep_all<<<dim3(8192 + 512), 256, 0, stream>>>(query, memory, w_q, w_m, w_qm, mmask,
                                                   a, c1s, qp, mb, mt);
    flash_fwd<<<dim3(512), 256, 0, stream>>>(qp, mb, mt, c1s, qmask, Opart, mlbuf);
    m2q_partial<<<dim3(BB * 16), 256, 0, stream>>>(mlbuf, a, qmask, query, partial, Zbuf);
    tail_kernel<<<dim3(8192 + 2048), 256, 0, stream>>>(Opart, mlbuf, partial, Zbuf,
                                                       out1, (float4*)out2);
}